// Round 4
// baseline (1785.437 us; speedup 1.0000x reference)
//
#include <hip/hip_runtime.h>

#define N_NODES  100000
#define N_EDGES  3200000
#define N_GRAPHS 512
#define F_IN     5
#define F_HID    16

#define BKT_SHIFT 7
#define BKT_NODES 128                         // nodes per bucket
#define NBKT ((N_NODES + BKT_NODES - 1) / BKT_NODES)   // 782
#define BKT_CAP 5120                          // mean 4092, +16 sigma
#define ACC_LD 17                             // padded LDS row stride (bank spread)

// ---------------- kernels ----------------

// zero cursor, out, cnt
__global__ void k_zero(int* __restrict__ cursor, float* __restrict__ out,
                       float* __restrict__ cnt) {
    int i = blockIdx.x * blockDim.x + threadIdx.x;
    if (i < NBKT) cursor[i] = 0;
    if (i < N_GRAPHS * F_HID) out[i] = 0.0f;
    if (i < N_GRAPHS) cnt[i] = 0.0f;
}

// partition: append packed (src<<7 | dst&127) to bucket dst>>7
__global__ void k_part(const int* __restrict__ src, const int* __restrict__ dst,
                       int* __restrict__ cursor, unsigned* __restrict__ packed) {
    int e = blockIdx.x * blockDim.x + threadIdx.x;
    if (e >= N_EDGES) return;
    int d = dst[e];
    int s = src[e];
    int b = d >> BKT_SHIFT;
    int slot = atomicAdd(&cursor[b], 1);
    if (slot < BKT_CAP)
        packed[(size_t)b * BKT_CAP + slot] =
            ((unsigned)s << BKT_SHIFT) | (unsigned)(d & (BKT_NODES - 1));
}

// per-bucket LDS histogram -> dinv = rsqrt(1 + deg)
__global__ void k_deg(const int* __restrict__ cursor, const unsigned* __restrict__ packed,
                      float* __restrict__ dinv) {
    __shared__ int c[BKT_NODES];
    int b = blockIdx.x, t = threadIdx.x;
    if (t < BKT_NODES) c[t] = 0;
    __syncthreads();
    int n = min(cursor[b], BKT_CAP);
    const unsigned* pk = packed + (size_t)b * BKT_CAP;
    for (int k = t; k < n; k += 256)
        atomicAdd(&c[pk[k] & (BKT_NODES - 1)], 1);
    __syncthreads();
    int node = b * BKT_NODES + t;
    if (t < BKT_NODES && node < N_NODES)
        dinv[node] = rsqrtf((float)(1 + c[t]));
}

// h = x @ W1 (5->16); p = h * dinv
__global__ void k_xform1(const float* __restrict__ x, const float* __restrict__ W1,
                         const float* __restrict__ dinv, float* __restrict__ p) {
    __shared__ float w[F_IN * F_HID];
    int t = threadIdx.x;
    if (t < F_IN * F_HID) w[t] = W1[t];
    __syncthreads();
    int i = blockIdx.x * blockDim.x + t;
    if (i >= N_NODES) return;
    float xi[F_IN];
#pragma unroll
    for (int k = 0; k < F_IN; k++) xi[k] = x[i * F_IN + k];
    float di = dinv[i];
#pragma unroll
    for (int c = 0; c < F_HID; c++) {
        float h = 0.0f;
#pragma unroll
        for (int k = 0; k < F_IN; k++) h += xi[k] * w[k * F_HID + c];
        p[i * F_HID + c] = h * di;
    }
}

// aggregate one bucket: LDS acc, thread-per-edge gather of p[src], then
// coalesced write-out with self-loop fused: S[i] = p[i] + acc[i]
__global__ void k_agg(const int* __restrict__ cursor, const unsigned* __restrict__ packed,
                      const float* __restrict__ p, float* __restrict__ S) {
    __shared__ float acc[BKT_NODES * ACC_LD];
    int b = blockIdx.x, t = threadIdx.x;
    for (int i = t; i < BKT_NODES * ACC_LD; i += 256) acc[i] = 0.0f;
    __syncthreads();
    int n = min(cursor[b], BKT_CAP);
    const unsigned* pk = packed + (size_t)b * BKT_CAP;
    const float4* p4 = (const float4*)p;
    for (int k = t; k < n; k += 256) {
        unsigned w = pk[k];
        int s  = w >> BKT_SHIFT;
        int dl = w & (BKT_NODES - 1);
        float4 v0 = p4[s * 4 + 0];
        float4 v1 = p4[s * 4 + 1];
        float4 v2 = p4[s * 4 + 2];
        float4 v3 = p4[s * 4 + 3];
        float* a = &acc[dl * ACC_LD];
        atomicAdd(a + 0,  v0.x); atomicAdd(a + 1,  v0.y);
        atomicAdd(a + 2,  v0.z); atomicAdd(a + 3,  v0.w);
        atomicAdd(a + 4,  v1.x); atomicAdd(a + 5,  v1.y);
        atomicAdd(a + 6,  v1.z); atomicAdd(a + 7,  v1.w);
        atomicAdd(a + 8,  v2.x); atomicAdd(a + 9,  v2.y);
        atomicAdd(a + 10, v2.z); atomicAdd(a + 11, v2.w);
        atomicAdd(a + 12, v3.x); atomicAdd(a + 13, v3.y);
        atomicAdd(a + 14, v3.z); atomicAdd(a + 15, v3.w);
    }
    __syncthreads();
    for (int i = t; i < BKT_NODES * 4; i += 256) {
        int dl = i >> 2, ch = i & 3;
        int node = b * BKT_NODES + dl;
        if (node < N_NODES) {
            float4 sv = p4[node * 4 + ch];            // self loop
            const float* a = &acc[dl * ACC_LD + ch * 4];
            sv.x += a[0]; sv.y += a[1]; sv.z += a[2]; sv.w += a[3];
            ((float4*)S)[node * 4 + ch] = sv;
        }
    }
}

// finalize layer1: h1 = relu(dinv*S + b1); p = (h1 @ W2) * dinv
__global__ void k_mid(const float* __restrict__ W2, const float* __restrict__ b1,
                      const float* __restrict__ dinv, const float* __restrict__ S,
                      float* __restrict__ p) {
    __shared__ float w[F_HID * F_HID];
    __shared__ float bb[F_HID];
    int t = threadIdx.x;
    if (t < F_HID * F_HID) w[t] = W2[t];
    if (t < F_HID) bb[t] = b1[t];
    __syncthreads();
    int i = blockIdx.x * blockDim.x + t;
    if (i >= N_NODES) return;
    float di = dinv[i];
    float h[F_HID];
#pragma unroll
    for (int c = 0; c < F_HID; c++) {
        float v = di * S[i * F_HID + c] + bb[c];
        h[c] = v > 0.0f ? v : 0.0f;
    }
#pragma unroll
    for (int c2 = 0; c2 < F_HID; c2++) {
        float m = 0.0f;
#pragma unroll
        for (int c = 0; c < F_HID; c++) m += h[c] * w[c * F_HID + c2];
        p[i * F_HID + c2] = m * di;
    }
}

// finalize layer2 + pool
__global__ void k_pool(const float* __restrict__ b2, const float* __restrict__ dinv,
                       const float* __restrict__ S, const int* __restrict__ batch,
                       float* __restrict__ out, float* __restrict__ cnt) {
    __shared__ float bb[F_HID];
    int t = threadIdx.x;
    if (t < F_HID) bb[t] = b2[t];
    __syncthreads();
    int i = blockIdx.x * blockDim.x + t;
    if (i >= N_NODES) return;
    float di = dinv[i];
    int g = batch[i];
#pragma unroll
    for (int c = 0; c < F_HID; c++) {
        float v = di * S[i * F_HID + c] + bb[c];
        v = v > 0.0f ? v : 0.0f;
        atomicAdd(&out[g * F_HID + c], v);
    }
    atomicAdd(&cnt[g], 1.0f);
}

__global__ void k_div(float* __restrict__ out, const float* __restrict__ cnt) {
    int i = blockIdx.x * blockDim.x + threadIdx.x;
    if (i < N_GRAPHS * F_HID) {
        float c = cnt[i / F_HID];
        out[i] /= fmaxf(c, 1.0f);
    }
}

// ---------------- launcher ----------------

extern "C" void kernel_launch(void* const* d_in, const int* in_sizes, int n_in,
                              void* d_out, int out_size, void* d_ws, size_t ws_size,
                              hipStream_t stream) {
    const float* x     = (const float*)d_in[0];
    const int*   ei    = (const int*)d_in[1];   // [2, N_EDGES]
    const int*   batch = (const int*)d_in[2];
    const float* W1    = (const float*)d_in[3];
    const float* b1    = (const float*)d_in[4];
    const float* W2    = (const float*)d_in[5];
    const float* b2    = (const float*)d_in[6];
    float* out = (float*)d_out;

    // workspace: cursor | packed | dinv | p | S | cnt   (~30 MB total)
    int*      cursor = (int*)d_ws;                                   // NBKT (pad 1024)
    unsigned* packed = (unsigned*)(cursor + 1024);                   // NBKT*BKT_CAP
    float*    dinv   = (float*)(packed + (size_t)NBKT * BKT_CAP);    // N
    float*    p      = dinv + N_NODES;                               // 16N
    float*    S      = p + (size_t)N_NODES * F_HID;                  // 16N
    float*    cnt    = S + (size_t)N_NODES * F_HID;                  // 512

    const int* src = ei;
    const int* dst = ei + N_EDGES;

    const int nb_nodes = (N_NODES + 255) / 256;
    const int nb_edges = (N_EDGES + 255) / 256;

    k_zero<<<(N_GRAPHS * F_HID + 255) / 256, 256, 0, stream>>>(cursor, out, cnt);
    k_part<<<nb_edges, 256, 0, stream>>>(src, dst, cursor, packed);
    k_deg<<<NBKT, 256, 0, stream>>>(cursor, packed, dinv);
    k_xform1<<<nb_nodes, 256, 0, stream>>>(x, W1, dinv, p);
    k_agg<<<NBKT, 256, 0, stream>>>(cursor, packed, p, S);
    k_mid<<<nb_nodes, 256, 0, stream>>>(W2, b1, dinv, S, p);
    k_agg<<<NBKT, 256, 0, stream>>>(cursor, packed, p, S);
    k_pool<<<nb_nodes, 256, 0, stream>>>(b2, dinv, S, batch, out, cnt);
    k_div<<<(N_GRAPHS * F_HID + 255) / 256, 256, 0, stream>>>(out, cnt);
}

// Round 5
// 274.245 us; speedup vs baseline: 6.5104x; 6.5104x over previous
//
#include <hip/hip_runtime.h>

#define N_NODES  100000
#define N_EDGES  3200000
#define N_GRAPHS 512
#define F_IN     5
#define F_HID    16

#define PBLK   512                      // k_part block size
#define CHUNK  8192                     // edges per k_part workgroup
#define NCHUNK ((N_EDGES + CHUNK - 1) / CHUNK)          // 391
#define BKT_NODES 256                   // nodes per coarse bucket
#define NBKT ((N_NODES + BKT_NODES - 1) / BKT_NODES)    // 391
#define CAP 10240                       // mean 8184, +22 sigma

// ---------------- kernels ----------------

__global__ void k_zero(int* __restrict__ cursor, float* __restrict__ out,
                       float* __restrict__ cnt) {
    int i = blockIdx.x * blockDim.x + threadIdx.x;
    if (i < NBKT) cursor[i] = 0;
    if (i < N_GRAPHS * F_HID) out[i] = 0.0f;
    if (i < N_GRAPHS) cnt[i] = 0.0f;
}

// staged counting-sort partition into 391 coarse buckets of dst>>8.
// one global atomic per (bucket, workgroup); coalesced run writes.
__global__ __launch_bounds__(PBLK) void k_part(const int* __restrict__ src,
                                               const int* __restrict__ dst,
                                               int* __restrict__ cursor,
                                               unsigned* __restrict__ packed) {
    __shared__ int hist[PBLK];
    __shared__ int scn[PBLK];
    __shared__ int rnk[PBLK];
    __shared__ int gbase[PBLK];
    __shared__ unsigned sorted[CHUNK];
    __shared__ unsigned short sbkt[CHUNK];
    int t = threadIdx.x;
    int chunk0 = blockIdx.x * CHUNK;
    int n = min(CHUNK, N_EDGES - chunk0);
    hist[t] = 0;
    __syncthreads();
    int ls[CHUNK / PBLK], ld[CHUNK / PBLK];
    for (int k = t, idx = 0; k < n; k += PBLK, idx++) {
        ls[idx] = src[chunk0 + k];
        ld[idx] = dst[chunk0 + k];
        atomicAdd(&hist[ld[idx] >> 8], 1);
    }
    __syncthreads();
    int v = hist[t];
    scn[t] = v;
    __syncthreads();
    for (int o = 1; o < PBLK; o <<= 1) {
        int add = (t >= o) ? scn[t - o] : 0;
        __syncthreads();
        scn[t] += add;
        __syncthreads();
    }
    int excl = scn[t] - v;
    rnk[t] = excl;
    gbase[t] = (t < NBKT && v > 0) ? atomicAdd(&cursor[t], v) : 0;
    __syncthreads();
    for (int k = t, idx = 0; k < n; k += PBLK, idx++) {
        int d = ld[idx], s = ls[idx];
        int b = d >> 8;
        int r = atomicAdd(&rnk[b], 1);
        sorted[r] = ((unsigned)s << 8) | (unsigned)(d & 255);
        sbkt[r] = (unsigned short)b;
    }
    __syncthreads();
    for (int k = t; k < n; k += PBLK) {
        int b = sbkt[k];
        int local = k - (scn[b] - hist[b]);          // position within this wg's run
        int g = gbase[b] + local;
        if (g < CAP) packed[(size_t)b * CAP + g] = sorted[k];
    }
}

// tiny serial scan of 391 bucket counts -> bktBase
__global__ void k_scanb(const int* __restrict__ cursor, int* __restrict__ bktBase) {
    if (threadIdx.x == 0 && blockIdx.x == 0) {
        int acc = 0;
        for (int b = 0; b < NBKT; b++) { bktBase[b] = acc; acc += min(cursor[b], CAP); }
        bktBase[NBKT] = acc;
    }
}

// per coarse bucket: node-level counting sort -> CSR col + row_ptr + dinv
__global__ __launch_bounds__(256) void k_csr(const int* __restrict__ cursor,
                                             const int* __restrict__ bktBase,
                                             const unsigned* __restrict__ packed,
                                             int* __restrict__ row_ptr,
                                             int* __restrict__ col,
                                             float* __restrict__ dinv) {
    __shared__ int hist[BKT_NODES];
    __shared__ int scn[BKT_NODES];
    __shared__ int rnk[BKT_NODES];
    __shared__ unsigned ed[CAP];
    int b = blockIdx.x, t = threadIdx.x;
    int n = min(cursor[b], CAP);
    int base = bktBase[b];
    hist[t] = 0;
    __syncthreads();
    const unsigned* pk = packed + (size_t)b * CAP;
    for (int k = t; k < n; k += 256) {
        unsigned w = pk[k];
        ed[k] = w;
        atomicAdd(&hist[w & 255], 1);
    }
    __syncthreads();
    int v = hist[t];
    scn[t] = v;
    __syncthreads();
    for (int o = 1; o < 256; o <<= 1) {
        int add = (t >= o) ? scn[t - o] : 0;
        __syncthreads();
        scn[t] += add;
        __syncthreads();
    }
    int excl = scn[t] - v;
    rnk[t] = excl;
    __syncthreads();
    for (int k = t; k < n; k += 256) {
        unsigned w = ed[k];
        int dl = w & 255;
        int r = atomicAdd(&rnk[dl], 1);
        col[base + r] = (int)(w >> 8);
    }
    int node = b * BKT_NODES + t;
    if (node < N_NODES) {
        row_ptr[node] = base + excl;
        dinv[node] = rsqrtf((float)(1 + v));
        if (node == N_NODES - 1) row_ptr[N_NODES] = base + excl + v;
    }
}

// h = x @ W1 (5->16); p = h * dinv
__global__ void k_xform1(const float* __restrict__ x, const float* __restrict__ W1,
                         const float* __restrict__ dinv, float* __restrict__ p) {
    __shared__ float w[F_IN * F_HID];
    int t = threadIdx.x;
    if (t < F_IN * F_HID) w[t] = W1[t];
    __syncthreads();
    int i = blockIdx.x * blockDim.x + t;
    if (i >= N_NODES) return;
    float xi[F_IN];
#pragma unroll
    for (int k = 0; k < F_IN; k++) xi[k] = x[i * F_IN + k];
    float di = dinv[i];
#pragma unroll
    for (int c = 0; c < F_HID; c++) {
        float h = 0.0f;
#pragma unroll
        for (int k = 0; k < F_IN; k++) h += xi[k] * w[k * F_HID + c];
        p[i * F_HID + c] = h * di;
    }
}

// pull: S[i] = p[i] (self loop) + sum over row of p[col[k]]; 4 threads per node
__global__ void k_pull(const int* __restrict__ row_ptr, const int* __restrict__ col,
                       const float* __restrict__ p, float* __restrict__ S) {
    int t = blockIdx.x * blockDim.x + threadIdx.x;
    int i = t >> 2;
    int j = t & 3;
    if (i >= N_NODES) return;
    int beg = row_ptr[i], end = row_ptr[i + 1];
    const float4* p4 = (const float4*)p;
    float4 acc = p4[i * 4 + j];
    for (int k = beg; k < end; k++) {
        int s = col[k];
        float4 v = p4[s * 4 + j];
        acc.x += v.x; acc.y += v.y; acc.z += v.z; acc.w += v.w;
    }
    ((float4*)S)[i * 4 + j] = acc;
}

// finalize layer1: h1 = relu(dinv*S + b1); p = (h1 @ W2) * dinv
__global__ void k_mid(const float* __restrict__ W2, const float* __restrict__ b1,
                      const float* __restrict__ dinv, const float* __restrict__ S,
                      float* __restrict__ p) {
    __shared__ float w[F_HID * F_HID];
    __shared__ float bb[F_HID];
    int t = threadIdx.x;
    if (t < F_HID * F_HID) w[t] = W2[t];
    if (t < F_HID) bb[t] = b1[t];
    __syncthreads();
    int i = blockIdx.x * blockDim.x + t;
    if (i >= N_NODES) return;
    float di = dinv[i];
    float h[F_HID];
#pragma unroll
    for (int c = 0; c < F_HID; c++) {
        float v = di * S[i * F_HID + c] + bb[c];
        h[c] = v > 0.0f ? v : 0.0f;
    }
#pragma unroll
    for (int c2 = 0; c2 < F_HID; c2++) {
        float m = 0.0f;
#pragma unroll
        for (int c = 0; c < F_HID; c++) m += h[c] * w[c * F_HID + c2];
        p[i * F_HID + c2] = m * di;
    }
}

// finalize layer2 + pool; batch is sorted so a block spans few graphs:
// LDS per-graph accumulation, few global atomics
__global__ void k_pool(const float* __restrict__ b2, const float* __restrict__ dinv,
                       const float* __restrict__ S, const int* __restrict__ batch,
                       float* __restrict__ out, float* __restrict__ cnt) {
    __shared__ float bb[F_HID];
    __shared__ float acc[16][F_HID];
    __shared__ int gcnt[16];
    __shared__ int g0s;
    int t = threadIdx.x;
    if (t < F_HID) bb[t] = b2[t];
    if (t < 16) gcnt[t] = 0;
    for (int i2 = t; i2 < 16 * F_HID; i2 += 256) ((float*)acc)[i2] = 0.0f;
    int blk0 = blockIdx.x * 256;
    if (t == 0) g0s = batch[blk0 < N_NODES ? blk0 : N_NODES - 1];
    __syncthreads();
    int g0 = g0s;
    int i = blk0 + t;
    if (i < N_NODES) {
        float di = dinv[i];
        int g = batch[i];
        int l = g - g0;
        float h[F_HID];
#pragma unroll
        for (int c = 0; c < F_HID; c++) {
            float v = di * S[i * F_HID + c] + bb[c];
            h[c] = v > 0.0f ? v : 0.0f;
        }
        if (l >= 0 && l < 16) {
#pragma unroll
            for (int c = 0; c < F_HID; c++) atomicAdd(&acc[l][c], h[c]);
            atomicAdd(&gcnt[l], 1);
        } else {
#pragma unroll
            for (int c = 0; c < F_HID; c++) atomicAdd(&out[g * F_HID + c], h[c]);
            atomicAdd(&cnt[g], 1.0f);
        }
    }
    __syncthreads();
    {
        int l = t >> 4, c = t & 15;           // t in [0,256): l in [0,16)
        if (gcnt[l] > 0) atomicAdd(&out[(g0 + l) * F_HID + c], acc[l][c]);
    }
    if (t < 16 && gcnt[t] > 0) atomicAdd(&cnt[g0 + t], (float)gcnt[t]);
}

__global__ void k_div(float* __restrict__ out, const float* __restrict__ cnt) {
    int i = blockIdx.x * blockDim.x + threadIdx.x;
    if (i < N_GRAPHS * F_HID) {
        float c = cnt[i / F_HID];
        out[i] /= fmaxf(c, 1.0f);
    }
}

// ---------------- launcher ----------------

extern "C" void kernel_launch(void* const* d_in, const int* in_sizes, int n_in,
                              void* d_out, int out_size, void* d_ws, size_t ws_size,
                              hipStream_t stream) {
    const float* x     = (const float*)d_in[0];
    const int*   ei    = (const int*)d_in[1];   // [2, N_EDGES]
    const int*   batch = (const int*)d_in[2];
    const float* W1    = (const float*)d_in[3];
    const float* b1    = (const float*)d_in[4];
    const float* W2    = (const float*)d_in[5];
    const float* b2    = (const float*)d_in[6];
    float* out = (float*)d_out;

    // workspace (~43 MB)
    int*      cursor  = (int*)d_ws;                                   // 391 (pad 512)
    int*      bktBase = cursor + 512;                                 // 392 (pad 512)
    unsigned* packed  = (unsigned*)(bktBase + 512);                   // NBKT*CAP
    int*      row_ptr = (int*)(packed + (size_t)NBKT * CAP);          // 100001 (pad 100352)
    int*      col     = row_ptr + 100352;                             // N_EDGES
    float*    dinv    = (float*)(col + N_EDGES);                      // N
    float*    p       = dinv + N_NODES;                               // 16N
    float*    S       = p + (size_t)N_NODES * F_HID;                  // 16N
    float*    cnt     = S + (size_t)N_NODES * F_HID;                  // 512

    const int* src = ei;
    const int* dst = ei + N_EDGES;

    const int nb_nodes = (N_NODES + 255) / 256;
    const int nb_pull  = (N_NODES * 4 + 255) / 256;

    k_zero<<<(N_GRAPHS * F_HID + 255) / 256, 256, 0, stream>>>(cursor, out, cnt);
    k_part<<<NCHUNK, PBLK, 0, stream>>>(src, dst, cursor, packed);
    k_scanb<<<1, 64, 0, stream>>>(cursor, bktBase);
    k_csr<<<NBKT, 256, 0, stream>>>(cursor, bktBase, packed, row_ptr, col, dinv);
    k_xform1<<<nb_nodes, 256, 0, stream>>>(x, W1, dinv, p);
    k_pull<<<nb_pull, 256, 0, stream>>>(row_ptr, col, p, S);
    k_mid<<<nb_nodes, 256, 0, stream>>>(W2, b1, dinv, S, p);
    k_pull<<<nb_pull, 256, 0, stream>>>(row_ptr, col, p, S);
    k_pool<<<nb_nodes, 256, 0, stream>>>(b2, dinv, S, batch, out, cnt);
    k_div<<<(N_GRAPHS * F_HID + 255) / 256, 256, 0, stream>>>(out, cnt);
}

// Round 6
// 223.665 us; speedup vs baseline: 7.9827x; 1.2261x over previous
//
#include <hip/hip_runtime.h>

#define N_NODES  100000
#define N_EDGES  3200000
#define N_GRAPHS 512
#define F_IN     5
#define F_HID    16

#define PBLK   512                      // k_part block size
#define CHUNK  8192                     // edges per k_part workgroup
#define NCHUNK ((N_EDGES + CHUNK - 1) / CHUNK)          // 391
#define BKT_NODES 256                   // nodes per coarse bucket
#define NBKT ((N_NODES + BKT_NODES - 1) / BKT_NODES)    // 391
#define CAP 10240                       // mean 8184, +22 sigma

// ---------------- helpers ----------------

__device__ inline unsigned short f2bf(float f) {
    unsigned u = __float_as_uint(f);
    return (unsigned short)((u + 0x7fffu + ((u >> 16) & 1u)) >> 16);   // RNE
}
__device__ inline float bf2f(unsigned short h) {
    return __uint_as_float(((unsigned)h) << 16);
}
__device__ inline float4 cvt4(ushort4 u) {
    return make_float4(bf2f(u.x), bf2f(u.y), bf2f(u.z), bf2f(u.w));
}

// block-wide inclusive scan via wave shfl; NW = number of waves (<=64)
template <int NW>
__device__ inline int block_incl_scan(int v, int t, int* wsum) {
    int lane = t & 63, wave = t >> 6;
    int x = v;
#pragma unroll
    for (int o = 1; o < 64; o <<= 1) {
        int y = __shfl_up(x, o, 64);
        if (lane >= o) x += y;
    }
    if (lane == 63) wsum[wave] = x;
    __syncthreads();
    if (t < 64) {
        int w = (t < NW) ? wsum[t] : 0;
#pragma unroll
        for (int o = 1; o < NW; o <<= 1) {
            int y = __shfl_up(w, o, 64);
            if (t >= o) w += y;
        }
        if (t < NW) wsum[t] = w;
    }
    __syncthreads();
    return x + (wave ? wsum[wave - 1] : 0);
}

// ---------------- kernels ----------------

__global__ void k_zero(int* __restrict__ cursor, float* __restrict__ out,
                       float* __restrict__ cnt) {
    int i = blockIdx.x * blockDim.x + threadIdx.x;
    if (i < NBKT) cursor[i] = 0;
    if (i < N_GRAPHS * F_HID) out[i] = 0.0f;
    if (i < N_GRAPHS) cnt[i] = 0.0f;
}

// staged counting-sort partition into 391 coarse buckets of dst>>8.
__global__ __launch_bounds__(PBLK) void k_part(const int* __restrict__ src,
                                               const int* __restrict__ dst,
                                               int* __restrict__ cursor,
                                               unsigned* __restrict__ packed) {
    __shared__ int scn[PBLK];       // exclusive prefix per bucket
    __shared__ int rnk[PBLK];
    __shared__ int gbase[PBLK];
    __shared__ int hist[PBLK];
    __shared__ int wsum[8];
    __shared__ unsigned sorted[CHUNK];
    __shared__ unsigned short sbkt[CHUNK];
    int t = threadIdx.x;
    int chunk0 = blockIdx.x * CHUNK;
    int n = min(CHUNK, N_EDGES - chunk0);
    hist[t] = 0;
    __syncthreads();
    int ls[CHUNK / PBLK], ld[CHUNK / PBLK];
    for (int k = t, idx = 0; k < n; k += PBLK, idx++) {
        ls[idx] = src[chunk0 + k];
        ld[idx] = dst[chunk0 + k];
        atomicAdd(&hist[ld[idx] >> 8], 1);
    }
    __syncthreads();
    int v = hist[t];
    int incl = block_incl_scan<8>(v, t, wsum);
    int excl = incl - v;
    scn[t] = excl;
    rnk[t] = excl;
    gbase[t] = (v > 0) ? atomicAdd(&cursor[t], v) : 0;
    __syncthreads();
    for (int k = t, idx = 0; k < n; k += PBLK, idx++) {
        int d = ld[idx], s = ls[idx];
        int b = d >> 8;
        int r = atomicAdd(&rnk[b], 1);
        sorted[r] = ((unsigned)s << 8) | (unsigned)(d & 255);
        sbkt[r] = (unsigned short)b;
    }
    __syncthreads();
    for (int k = t; k < n; k += PBLK) {
        int b = sbkt[k];
        int g = gbase[b] + (k - scn[b]);
        if (g < CAP) packed[(size_t)b * CAP + g] = sorted[k];
    }
}

// parallel exclusive scan of 391 bucket counts -> bktBase
__global__ __launch_bounds__(512) void k_scanb(const int* __restrict__ cursor,
                                               int* __restrict__ bktBase) {
    __shared__ int wsum[8];
    int t = threadIdx.x;
    int v = (t < NBKT) ? min(cursor[t], CAP) : 0;
    int incl = block_incl_scan<8>(v, t, wsum);
    if (t < NBKT) bktBase[t] = incl - v;
    if (t == NBKT - 1) bktBase[NBKT] = incl;
}

// per coarse bucket: node-level counting sort -> CSR col + row_ptr + dinv
__global__ __launch_bounds__(256) void k_csr(const int* __restrict__ cursor,
                                             const int* __restrict__ bktBase,
                                             const unsigned* __restrict__ packed,
                                             int* __restrict__ row_ptr,
                                             int* __restrict__ col,
                                             float* __restrict__ dinv) {
    __shared__ int hist[BKT_NODES];
    __shared__ int rnk[BKT_NODES];
    __shared__ int wsum[4];
    __shared__ unsigned ed[CAP];
    int b = blockIdx.x, t = threadIdx.x;
    int n = min(cursor[b], CAP);
    int base = bktBase[b];
    hist[t] = 0;
    __syncthreads();
    const unsigned* pk = packed + (size_t)b * CAP;
    for (int k = t; k < n; k += 256) {
        unsigned w = pk[k];
        ed[k] = w;
        atomicAdd(&hist[w & 255], 1);
    }
    __syncthreads();
    int v = hist[t];
    int incl = block_incl_scan<4>(v, t, wsum);
    int excl = incl - v;
    rnk[t] = excl;
    __syncthreads();
    for (int k = t; k < n; k += 256) {
        unsigned w = ed[k];
        int r = atomicAdd(&rnk[w & 255], 1);
        col[base + r] = (int)(w >> 8);
    }
    int node = b * BKT_NODES + t;
    if (node < N_NODES) {
        row_ptr[node] = base + excl;
        dinv[node] = rsqrtf((float)(1 + v));
        if (node == N_NODES - 1) row_ptr[N_NODES] = base + excl + v;
    }
}

// h = x @ W1 (5->16); pb = bf16(h * dinv)
__global__ void k_xform1(const float* __restrict__ x, const float* __restrict__ W1,
                         const float* __restrict__ dinv,
                         unsigned short* __restrict__ pb) {
    __shared__ float w[F_IN * F_HID];
    int t = threadIdx.x;
    if (t < F_IN * F_HID) w[t] = W1[t];
    __syncthreads();
    int i = blockIdx.x * blockDim.x + t;
    if (i >= N_NODES) return;
    float xi[F_IN];
#pragma unroll
    for (int k = 0; k < F_IN; k++) xi[k] = x[i * F_IN + k];
    float di = dinv[i];
    float hv[F_HID];
#pragma unroll
    for (int c = 0; c < F_HID; c++) {
        float h = 0.0f;
#pragma unroll
        for (int k = 0; k < F_IN; k++) h += xi[k] * w[k * F_HID + c];
        hv[c] = h * di;
    }
    unsigned pk[8];
#pragma unroll
    for (int q = 0; q < 8; q++)
        pk[q] = (unsigned)f2bf(hv[2 * q]) | ((unsigned)f2bf(hv[2 * q + 1]) << 16);
    uint4* d4 = (uint4*)(pb + (size_t)i * F_HID);
    d4[0] = make_uint4(pk[0], pk[1], pk[2], pk[3]);
    d4[1] = make_uint4(pk[4], pk[5], pk[6], pk[7]);
}

// pull: S[i] = pb[i] + sum over row of pb[col[k]]; 4 threads/node, fp32 acc
__global__ void k_pull(const int* __restrict__ row_ptr, const int* __restrict__ col,
                       const unsigned short* __restrict__ pb, float* __restrict__ S) {
    int t = blockIdx.x * blockDim.x + threadIdx.x;
    int i = t >> 2;
    int j = t & 3;
    if (i >= N_NODES) return;
    int beg = row_ptr[i], end = row_ptr[i + 1];
    const ushort4* pb4 = (const ushort4*)pb;
    float4 v0 = cvt4(pb4[i * 4 + j]);                 // self loop
    float4 acc = v0;
    int k = beg;
    for (; k + 3 < end; k += 4) {
        int s0 = col[k], s1 = col[k + 1], s2 = col[k + 2], s3 = col[k + 3];
        ushort4 a = pb4[s0 * 4 + j];
        ushort4 b = pb4[s1 * 4 + j];
        ushort4 c = pb4[s2 * 4 + j];
        ushort4 d = pb4[s3 * 4 + j];
        float4 fa = cvt4(a), fb = cvt4(b), fc = cvt4(c), fd = cvt4(d);
        acc.x += fa.x + fb.x + fc.x + fd.x;
        acc.y += fa.y + fb.y + fc.y + fd.y;
        acc.z += fa.z + fb.z + fc.z + fd.z;
        acc.w += fa.w + fb.w + fc.w + fd.w;
    }
    for (; k < end; k++) {
        float4 f = cvt4(pb4[col[k] * 4 + j]);
        acc.x += f.x; acc.y += f.y; acc.z += f.z; acc.w += f.w;
    }
    ((float4*)S)[i * 4 + j] = acc;
}

// finalize layer1: h1 = relu(dinv*S + b1); pb = bf16((h1 @ W2) * dinv)
__global__ void k_mid(const float* __restrict__ W2, const float* __restrict__ b1,
                      const float* __restrict__ dinv, const float* __restrict__ S,
                      unsigned short* __restrict__ pb) {
    __shared__ float w[F_HID * F_HID];
    __shared__ float bb[F_HID];
    int t = threadIdx.x;
    if (t < F_HID * F_HID) w[t] = W2[t];
    if (t < F_HID) bb[t] = b1[t];
    __syncthreads();
    int i = blockIdx.x * blockDim.x + t;
    if (i >= N_NODES) return;
    float di = dinv[i];
    float h[F_HID];
#pragma unroll
    for (int c = 0; c < F_HID; c++) {
        float v = di * S[i * F_HID + c] + bb[c];
        h[c] = v > 0.0f ? v : 0.0f;
    }
    float hv[F_HID];
#pragma unroll
    for (int c2 = 0; c2 < F_HID; c2++) {
        float m = 0.0f;
#pragma unroll
        for (int c = 0; c < F_HID; c++) m += h[c] * w[c * F_HID + c2];
        hv[c2] = m * di;
    }
    unsigned pk[8];
#pragma unroll
    for (int q = 0; q < 8; q++)
        pk[q] = (unsigned)f2bf(hv[2 * q]) | ((unsigned)f2bf(hv[2 * q + 1]) << 16);
    uint4* d4 = (uint4*)(pb + (size_t)i * F_HID);
    d4[0] = make_uint4(pk[0], pk[1], pk[2], pk[3]);
    d4[1] = make_uint4(pk[4], pk[5], pk[6], pk[7]);
}

// finalize layer2 + pool; batch sorted -> LDS per-graph accumulation
__global__ void k_pool(const float* __restrict__ b2, const float* __restrict__ dinv,
                       const float* __restrict__ S, const int* __restrict__ batch,
                       float* __restrict__ out, float* __restrict__ cnt) {
    __shared__ float bb[F_HID];
    __shared__ float acc[16][F_HID];
    __shared__ int gcnt[16];
    __shared__ int g0s;
    int t = threadIdx.x;
    if (t < F_HID) bb[t] = b2[t];
    if (t < 16) gcnt[t] = 0;
    for (int i2 = t; i2 < 16 * F_HID; i2 += 256) ((float*)acc)[i2] = 0.0f;
    int blk0 = blockIdx.x * 256;
    if (t == 0) g0s = batch[blk0 < N_NODES ? blk0 : N_NODES - 1];
    __syncthreads();
    int g0 = g0s;
    int i = blk0 + t;
    if (i < N_NODES) {
        float di = dinv[i];
        int g = batch[i];
        int l = g - g0;
        float h[F_HID];
#pragma unroll
        for (int c = 0; c < F_HID; c++) {
            float v = di * S[i * F_HID + c] + bb[c];
            h[c] = v > 0.0f ? v : 0.0f;
        }
        if (l >= 0 && l < 16) {
#pragma unroll
            for (int c = 0; c < F_HID; c++) atomicAdd(&acc[l][c], h[c]);
            atomicAdd(&gcnt[l], 1);
        } else {
#pragma unroll
            for (int c = 0; c < F_HID; c++) atomicAdd(&out[g * F_HID + c], h[c]);
            atomicAdd(&cnt[g], 1.0f);
        }
    }
    __syncthreads();
    {
        int l = t >> 4, c = t & 15;
        if (gcnt[l] > 0) atomicAdd(&out[(g0 + l) * F_HID + c], acc[l][c]);
    }
    if (t < 16 && gcnt[t] > 0) atomicAdd(&cnt[g0 + t], (float)gcnt[t]);
}

__global__ void k_div(float* __restrict__ out, const float* __restrict__ cnt) {
    int i = blockIdx.x * blockDim.x + threadIdx.x;
    if (i < N_GRAPHS * F_HID) {
        float c = cnt[i / F_HID];
        out[i] /= fmaxf(c, 1.0f);
    }
}

// ---------------- launcher ----------------

extern "C" void kernel_launch(void* const* d_in, const int* in_sizes, int n_in,
                              void* d_out, int out_size, void* d_ws, size_t ws_size,
                              hipStream_t stream) {
    const float* x     = (const float*)d_in[0];
    const int*   ei    = (const int*)d_in[1];   // [2, N_EDGES]
    const int*   batch = (const int*)d_in[2];
    const float* W1    = (const float*)d_in[3];
    const float* b1    = (const float*)d_in[4];
    const float* W2    = (const float*)d_in[5];
    const float* b2    = (const float*)d_in[6];
    float* out = (float*)d_out;

    int*            cursor  = (int*)d_ws;                                  // 512
    int*            bktBase = cursor + 512;                                // 512
    unsigned*       packed  = (unsigned*)(bktBase + 512);                  // NBKT*CAP
    int*            row_ptr = (int*)(packed + (size_t)NBKT * CAP);         // 100352
    int*            col     = row_ptr + 100352;                            // N_EDGES
    float*          dinv    = (float*)(col + N_EDGES);                     // N
    unsigned short* pb      = (unsigned short*)(dinv + N_NODES);           // 16N ushort
    float*          S       = (float*)(pb + (size_t)N_NODES * F_HID);      // 16N
    float*          cnt     = S + (size_t)N_NODES * F_HID;                 // 512

    const int* src = ei;
    const int* dst = ei + N_EDGES;

    const int nb_nodes = (N_NODES + 255) / 256;
    const int nb_pull  = (N_NODES * 4 + 255) / 256;

    k_zero<<<(N_GRAPHS * F_HID + 255) / 256, 256, 0, stream>>>(cursor, out, cnt);
    k_part<<<NCHUNK, PBLK, 0, stream>>>(src, dst, cursor, packed);
    k_scanb<<<1, 512, 0, stream>>>(cursor, bktBase);
    k_csr<<<NBKT, 256, 0, stream>>>(cursor, bktBase, packed, row_ptr, col, dinv);
    k_xform1<<<nb_nodes, 256, 0, stream>>>(x, W1, dinv, pb);
    k_pull<<<nb_pull, 256, 0, stream>>>(row_ptr, col, pb, S);
    k_mid<<<nb_nodes, 256, 0, stream>>>(W2, b1, dinv, S, pb);
    k_pull<<<nb_pull, 256, 0, stream>>>(row_ptr, col, pb, S);
    k_pool<<<nb_nodes, 256, 0, stream>>>(b2, dinv, S, batch, out, cnt);
    k_div<<<(N_GRAPHS * F_HID + 255) / 256, 256, 0, stream>>>(out, cnt);
}